// Round 10
// baseline (211.417 us; speedup 1.0000x reference)
//
#include <hip/hip_runtime.h>
#include <hip/hip_bf16.h>

#define SEQ 240
#define HID 4096
#define NH 16
#define HD 256

typedef float f32x4 __attribute__((ext_vector_type(4)));
typedef short s16x8 __attribute__((ext_vector_type(8)));
typedef short s16x4 __attribute__((ext_vector_type(4)));

__device__ __forceinline__ short f2bf(float f) {
    unsigned u = __builtin_bit_cast(unsigned, f);
    unsigned r = u + 0x7FFFu + ((u >> 16) & 1u);
    return (short)(r >> 16);
}

__device__ __forceinline__ s16x8 cvt8(float4 a, float4 b) {
    s16x8 r;
    r[0] = f2bf(a.x); r[1] = f2bf(a.y); r[2] = f2bf(a.z); r[3] = f2bf(a.w);
    r[4] = f2bf(b.x); r[5] = f2bf(b.y); r[6] = f2bf(b.z); r[7] = f2bf(b.w);
    return r;
}

// 8 f32 -> 8 bf16 via v_cvt_pk_bf16_f32 (RTNE), 4 instrs (m240: no builtin).
__device__ __forceinline__ s16x8 cvtpk8(f32x4 a, f32x4 b) {
    union { unsigned u[4]; s16x8 s; } r;
    asm("v_cvt_pk_bf16_f32 %0, %1, %2" : "=v"(r.u[0]) : "v"(a[0]), "v"(a[1]));
    asm("v_cvt_pk_bf16_f32 %0, %1, %2" : "=v"(r.u[1]) : "v"(a[2]), "v"(a[3]));
    asm("v_cvt_pk_bf16_f32 %0, %1, %2" : "=v"(r.u[2]) : "v"(b[0]), "v"(b[1]));
    asm("v_cvt_pk_bf16_f32 %0, %1, %2" : "=v"(r.u[3]) : "v"(b[2]), "v"(b[3]));
    return r.s;
}

// ---------------------------------------------------------------------------
// Kernel 0: convert inputs f32[240][4096] -> bf16 [256][4096], rows >=240 = 0
// ---------------------------------------------------------------------------
__global__ __launch_bounds__(256) void cvt_kernel(
    const float* __restrict__ in1, const float* __restrict__ in2,
    short* __restrict__ A1, short* __restrict__ A2)
{
    const int i = blockIdx.x * 256 + threadIdx.x;   // chunk of 8 elems
    const float* __restrict__ src = blockIdx.y ? in2 : in1;
    short* __restrict__ dst = blockIdx.y ? A2 : A1;
    const int r = i >> 9;
    const int c = (i & 511) * 8;
    s16x8 v = (s16x8){0,0,0,0,0,0,0,0};
    if (r < SEQ) {
        float4 a = *(const float4*)&src[(size_t)r * HID + c];
        float4 b = *(const float4*)&src[(size_t)r * HID + c + 4];
        v = cvt8(a, b);
    }
    *(s16x8*)&dst[(size_t)r * HID + c] = v;
}

// ---------------------------------------------------------------------------
// Kernel 1: QKV gemm partials — BARRIER-FREE REGISTER STREAMING.
// No LDS.  Each wave owns 64 rows x 32 cols; explicit distance-1 register
// double-buffer (named sets aA/wA, aB/wB) keeps 16 loads in flight while the
// previous tile's 16 MFMA run.  W f32->bf16 via v_cvt_pk (16 instr/step).
// BM=256, BN=32, BK=64; grid (128, 3, KS) = 1536 blocks @ KS=4.
// W read from HBM exactly once (4 waves of a block share via L2).
// A (bf16, L2-resident, exact fragment layout) direct loads.
// v (g==2) partials stored TRANSPOSED: pvt[z][n][m].
// ---------------------------------------------------------------------------
__global__ __launch_bounds__(256, 2) void qkv_gemm(
    const short* __restrict__ A1, const short* __restrict__ A2,
    const float* __restrict__ Wq, const float* __restrict__ Wk,
    const float* __restrict__ Wv,
    float* __restrict__ pqk, float* __restrict__ pvt, int KC)
{
    const int g  = blockIdx.y;
    const int z  = blockIdx.z;
    const int nb = blockIdx.x * 32;
    const short* __restrict__ A = (g == 0) ? A1 : A2;
    const float* __restrict__ W = (g == 0) ? Wq : (g == 1) ? Wk : Wv;

    const int tid  = threadIdx.x;
    const int lane = tid & 63;
    const int wm   = tid >> 6;    // wave owns rows wm*64 .. +63
    const int lr   = lane & 15;
    const int lg   = lane >> 4;

    f32x4 acc[4][2];
    #pragma unroll
    for (int m = 0; m < 4; ++m)
        #pragma unroll
        for (int n = 0; n < 2; ++n)
            acc[m][n] = (f32x4){0.f, 0.f, 0.f, 0.f};

    const short* __restrict__ ap = A + (size_t)(wm * 64 + lr) * HID + (size_t)z * KC + lg * 8;
    const float* __restrict__ wp = W + (size_t)(nb + lr) * HID + (size_t)z * KC + lg * 8;

    s16x8 aA[8], aB[8];           // A frags [m*2+ks], even/odd tile sets
    f32x4 wA[8], wB[8];           // W raw   [(n*2+ks)*2 + half]

#define LOAD_A(dst, kk) { _Pragma("unroll")                                   \
    for (int m = 0; m < 4; ++m) { _Pragma("unroll")                           \
      for (int ks = 0; ks < 2; ++ks)                                          \
        dst[m*2+ks] = *(const s16x8*)(ap + (size_t)m * 16 * HID + (kk) + ks * 32); } }

#define LOAD_W(dst, kk) { _Pragma("unroll")                                   \
    for (int n = 0; n < 2; ++n) { _Pragma("unroll")                           \
      for (int ks = 0; ks < 2; ++ks) {                                        \
        const float* s_ = wp + (size_t)n * 16 * HID + (kk) + ks * 32;         \
        dst[(n*2+ks)*2]   = *(const f32x4*)s_;                                \
        dst[(n*2+ks)*2+1] = *(const f32x4*)(s_ + 4); } } }

#define COMPUTE(aC, wC) { _Pragma("unroll")                                   \
    for (int n = 0; n < 2; ++n) { _Pragma("unroll")                           \
      for (int ks = 0; ks < 2; ++ks) {                                        \
        s16x8 bf_ = cvtpk8(wC[(n*2+ks)*2], wC[(n*2+ks)*2+1]);                 \
        _Pragma("unroll")                                                     \
        for (int m = 0; m < 4; ++m)                                           \
          acc[m][n] = __builtin_amdgcn_mfma_f32_16x16x32_bf16(                \
              aC[m*2+ks], bf_, acc[m][n], 0, 0, 0); } } }

    const int NIT = KC / 64;      // 16 @ KS=4 (even)

    LOAD_A(aA, 0)
    LOAD_W(wA, 0)
    int kn = 64;
    for (int t = 0; t < NIT; t += 2) {
        // prefetch t+1 into set B, then compute t from set A
        if (t + 1 < NIT) { LOAD_A(aB, kn) LOAD_W(wB, kn) kn += 64; }
        COMPUTE(aA, wA)
        // prefetch t+2 into set A, then compute t+1 from set B
        if (t + 2 < NIT) { LOAD_A(aA, kn) LOAD_W(wA, kn) kn += 64; }
        if (t + 1 < NIT) COMPUTE(aB, wB)
    }

#undef LOAD_A
#undef LOAD_W
#undef COMPUTE

    if (g == 2) {
        // transposed partial store: pvt[z][n][m]
        float* pout = pvt + (size_t)z * HID * SEQ;
        #pragma unroll
        for (int m = 0; m < 4; ++m) {
            const int row0 = wm * 64 + m * 16 + lg * 4;
            if (row0 >= SEQ) continue;
            #pragma unroll
            for (int n = 0; n < 2; ++n) {
                const int col = nb + n * 16 + lr;
                float4 o = make_float4(acc[m][n][0], acc[m][n][1], acc[m][n][2], acc[m][n][3]);
                *(float4*)&pout[(size_t)col * SEQ + row0] = o;
            }
        }
    } else {
        float* pout = pqk + (size_t)(z * 2 + g) * SEQ * HID;
        #pragma unroll
        for (int m = 0; m < 4; ++m) {
            const int row0 = wm * 64 + m * 16 + lg * 4;
            if (row0 >= SEQ) continue;
            #pragma unroll
            for (int n = 0; n < 2; ++n) {
                const int col = nb + n * 16 + lr;
                #pragma unroll
                for (int r = 0; r < 4; ++r)
                    pout[(size_t)(row0 + r) * HID + col] = acc[m][n][r];
            }
        }
    }
}

// ---------------------------------------------------------------------------
// Kernel 2: reduce q/k partials + bias -> bf16 row-major
// ---------------------------------------------------------------------------
__global__ __launch_bounds__(256) void reduce_qk(
    const float* __restrict__ pqk,
    const float* __restrict__ bq, const float* __restrict__ bk,
    short* __restrict__ qb, short* __restrict__ kb, int KS)
{
    const int g   = blockIdx.y;
    const int idx = blockIdx.x * 256 + threadIdx.x;   // f32x4 index
    f32x4 s = (f32x4){0.f, 0.f, 0.f, 0.f};
    for (int z = 0; z < KS; ++z)
        s += *(const f32x4*)&pqk[(size_t)(z * 2 + g) * SEQ * HID + (size_t)idx * 4];
    const int n = (idx * 4) & (HID - 1);
    const float* bias = g ? bk : bq;
    s += *(const f32x4*)&bias[n];
    short* ob = g ? kb : qb;
    s16x4 o = (s16x4){f2bf(s[0]), f2bf(s[1]), f2bf(s[2]), f2bf(s[3])};
    *(s16x4*)&ob[(size_t)idx * 4] = o;
}

// ---------------------------------------------------------------------------
// Kernel 3: reduce transposed v partials + bias -> vtb bf16 [4096][240]
// ---------------------------------------------------------------------------
__global__ __launch_bounds__(256) void reduce_v(
    const float* __restrict__ pvt, const float* __restrict__ bv,
    short* __restrict__ vtb, int KS)
{
    const int idx = blockIdx.x * 256 + threadIdx.x;   // f32x4 index over [4096][240]
    f32x4 s = (f32x4){0.f, 0.f, 0.f, 0.f};
    for (int z = 0; z < KS; ++z)
        s += *(const f32x4*)&pvt[(size_t)z * HID * SEQ + (size_t)idx * 4];
    const int n = idx / 60;                           // 60 f32x4 per 240-row
    const float b = bv[n];
    s16x4 o = (s16x4){f2bf(s[0] + b), f2bf(s[1] + b), f2bf(s[2] + b), f2bf(s[3] + b)};
    *(s16x4*)&vtb[(size_t)idx * 4] = o;
}

// ---------------------------------------------------------------------------
// Kernel 4: scores + softmax.  4 waves/block, jt-split, LDS cross-wave
// softmax combine.  P^T stored bf16: ptb[h][j][i].
// ---------------------------------------------------------------------------
__global__ __launch_bounds__(256) void scores_kernel(
    const short* __restrict__ qb, const short* __restrict__ kb,
    short* __restrict__ ptb)
{
    const int it   = blockIdx.x;     // 0..14
    const int h    = blockIdx.y;     // 0..15
    const int tid  = threadIdx.x;
    const int lane = tid & 63;
    const int w    = tid >> 6;
    const int lr   = lane & 15;
    const int lg   = lane >> 4;
    const int jt0  = w * 4;
    const int NJT  = (w < 3) ? 4 : 3;

    __shared__ float redmax[4][16];
    __shared__ float redsum[4][16];

    f32x4 acc[4];
    #pragma unroll
    for (int j = 0; j < 4; ++j) acc[j] = (f32x4){0.f, 0.f, 0.f, 0.f};

    const int ib = it * 16;
    const short* qrow = &qb[(size_t)(ib + lr) * HID + h * HD + lg * 8];

    for (int d0 = 0; d0 < HD; d0 += 32) {
        s16x8 afr = *(const s16x8*)&qrow[d0];
        #pragma unroll
        for (int j = 0; j < 4; ++j) {
            if (j < NJT) {
                s16x8 bfr = *(const s16x8*)&kb[(size_t)((jt0 + j) * 16 + lr) * HID + h * HD + d0 + lg * 8];
                acc[j] = __builtin_amdgcn_mfma_f32_16x16x32_bf16(afr, bfr, acc[j], 0, 0, 0);
            }
        }
    }

    const float sc = 0.0625f;
    #pragma unroll
    for (int j = 0; j < 4; ++j) acc[j] *= sc;

    // phase 1: wave-local max per i, publish
    #pragma unroll
    for (int r = 0; r < 4; ++r) {
        float mx = -1e30f;
        #pragma unroll
        for (int j = 0; j < 4; ++j) if (j < NJT) mx = fmaxf(mx, acc[j][r]);
        #pragma unroll
        for (int s = 1; s < 16; s <<= 1) mx = fmaxf(mx, __shfl_xor(mx, s, 64));
        if (lr == 0) redmax[w][lg * 4 + r] = mx;
    }
    __syncthreads();
    // phase 2: global max, exp, wave-local sum, publish
    #pragma unroll
    for (int r = 0; r < 4; ++r) {
        const int i = lg * 4 + r;
        float mx = fmaxf(fmaxf(redmax[0][i], redmax[1][i]),
                         fmaxf(redmax[2][i], redmax[3][i]));
        float sum = 0.f;
        #pragma unroll
        for (int j = 0; j < 4; ++j) {
            if (j < NJT) {
                float e = expf(acc[j][r] - mx);
                acc[j][r] = e;
                sum += e;
            }
        }
        #pragma unroll
        for (int s = 1; s < 16; s <<= 1) sum += __shfl_xor(sum, s, 64);
        if (lr == 0) redsum[w][i] = sum;
    }
    __syncthreads();
    // phase 3: normalize + store bf16 (4 consecutive i per lane)
    #pragma unroll
    for (int r = 0; r < 4; ++r) {
        const int i = lg * 4 + r;
        const float inv = 1.f / (redsum[0][i] + redsum[1][i] + redsum[2][i] + redsum[3][i]);
        #pragma unroll
        for (int j = 0; j < 4; ++j) if (j < NJT) acc[j][r] *= inv;
    }
    #pragma unroll
    for (int j = 0; j < 4; ++j) {
        if (j < NJT) {
            const int jj = (jt0 + j) * 16 + lr;
            s16x4 o = (s16x4){f2bf(acc[j][0]), f2bf(acc[j][1]), f2bf(acc[j][2]), f2bf(acc[j][3])};
            *(s16x4*)&ptb[(size_t)(h * SEQ + jj) * SEQ + ib + lg * 4] = o;
        }
    }
}

// ---------------------------------------------------------------------------
// Kernel 5: O = P^T V per head, 4 waves/block jt-split, all-bf16 inputs.
// ---------------------------------------------------------------------------
__global__ __launch_bounds__(256) void pv_kernel(
    const short* __restrict__ ptb, const short* __restrict__ vtb,
    float* __restrict__ out)
{
    const int dt   = blockIdx.x;     // 0..15
    const int h    = blockIdx.y;
    const int tid  = threadIdx.x;
    const int lane = tid & 63;
    const int w    = tid >> 6;
    const int lr   = lane & 15;
    const int lg   = lane >> 4;
    const int NJT  = (w < 3) ? 4 : 3;

    f32x4 acc[4];
    #pragma unroll
    for (int j = 0; j < 4; ++j) acc[j] = (f32x4){0.f, 0.f, 0.f, 0.f};

    const short* vrow = &vtb[(size_t)(h * HD + dt * 16 + lr) * SEQ + lg * 8];

    for (int i0 = 0; i0 < 256; i0 += 32) {
        const bool ok = (i0 + lg * 8) < SEQ;
        s16x8 bfr = (s16x8){0,0,0,0,0,0,0,0};
        if (ok) bfr = *(const s16x8*)&vrow[i0];
        #pragma unroll
        for (int j = 0; j < 4; ++j) {
            if (j < NJT) {
                const int jt = w + j * 4;
                s16x8 afr = (s16x8){0,0,0,0,0,0,0,0};
                if (ok) afr = *(const s16x8*)&ptb[(size_t)(h * SEQ + jt * 16 + lr) * SEQ + i0 + lg * 8];
                acc[j] = __builtin_amdgcn_mfma_f32_16x16x32_bf16(afr, bfr, acc[j], 0, 0, 0);
            }
        }
    }

    #pragma unroll
    for (int j = 0; j < 4; ++j) {
        if (j < NJT) {
            const int jt = w + j * 4;
            #pragma unroll
            for (int r = 0; r < 4; ++r)
                out[(size_t)(jt * 16 + lg * 4 + r) * HID + h * HD + dt * 16 + lr] = acc[j][r];
        }
    }
}

extern "C" void kernel_launch(void* const* d_in, const int* in_sizes, int n_in,
                              void* d_out, int out_size, void* d_ws, size_t ws_size,
                              hipStream_t stream) {
    const float* in1 = (const float*)d_in[0];
    const float* in2 = (const float*)d_in[1];
    const float* Wq  = (const float*)d_in[2];
    const float* bq  = (const float*)d_in[3];
    const float* Wk  = (const float*)d_in[4];
    const float* bk  = (const float*)d_in[5];
    const float* Wv  = (const float*)d_in[6];
    const float* bv  = (const float*)d_in[7];
    float* out = (float*)d_out;

    char* w = (char*)d_ws;
    short* A1  = (short*)w;  w += (size_t)256 * HID * 2;        // 2 MB
    short* A2  = (short*)w;  w += (size_t)256 * HID * 2;        // 2 MB
    short* qb  = (short*)w;  w += (size_t)SEQ * HID * 2;        // 1.97 MB
    short* kb  = (short*)w;  w += (size_t)SEQ * HID * 2;
    short* vtb = (short*)w;  w += (size_t)HID * SEQ * 2;
    short* ptb = (short*)w;  w += (size_t)NH * SEQ * SEQ * 2;   // 1.84 MB
    float* pqk = (float*)w;
    const size_t fixed  = (size_t)(w - (char*)d_ws);
    const size_t perKS  = ((size_t)2 * SEQ * HID + (size_t)HID * SEQ) * sizeof(float); // 11.8 MB

    int KS = 1;
    if (fixed + 4 * perKS <= ws_size)      KS = 4;
    else if (fixed + 2 * perKS <= ws_size) KS = 2;
    const int KC = HID / KS;
    float* pvt = pqk + (size_t)KS * 2 * SEQ * HID;

    cvt_kernel<<<dim3(512, 2), 256, 0, stream>>>(in1, in2, A1, A2);
    qkv_gemm<<<dim3(128, 3, KS), 256, 0, stream>>>(A1, A2, Wq, Wk, Wv, pqk, pvt, KC);
    reduce_qk<<<dim3(960, 2), 256, 0, stream>>>(pqk, bq, bk, qb, kb, KS);
    reduce_v<<<960, 256, 0, stream>>>(pvt, bv, vtb, KS);
    scores_kernel<<<dim3(15, 16), 256, 0, stream>>>(qb, kb, ptb);
    pv_kernel<<<dim3(16, 16), 256, 0, stream>>>(ptb, vtb, out);
}

// Round 11
// 106.493 us; speedup vs baseline: 1.9853x; 1.9853x over previous
//
#include <hip/hip_runtime.h>
#include <hip/hip_bf16.h>

#define SEQ 240
#define HID 4096
#define NH 16
#define HD 256

typedef float f32x4 __attribute__((ext_vector_type(4)));
typedef short s16x8 __attribute__((ext_vector_type(8)));
typedef short s16x4 __attribute__((ext_vector_type(4)));

__device__ __forceinline__ short f2bf(float f) {
    unsigned u = __builtin_bit_cast(unsigned, f);
    unsigned r = u + 0x7FFFu + ((u >> 16) & 1u);
    return (short)(r >> 16);
}

__device__ __forceinline__ s16x8 cvt8(float4 a, float4 b) {
    s16x8 r;
    r[0] = f2bf(a.x); r[1] = f2bf(a.y); r[2] = f2bf(a.z); r[3] = f2bf(a.w);
    r[4] = f2bf(b.x); r[5] = f2bf(b.y); r[6] = f2bf(b.z); r[7] = f2bf(b.w);
    return r;
}

// 8 f32 -> 8 bf16 via v_cvt_pk_bf16_f32 (verified numerics in r10, absmax ok)
__device__ __forceinline__ s16x8 cvtpk8(f32x4 a, f32x4 b) {
    union { unsigned u[4]; s16x8 s; } r;
    asm("v_cvt_pk_bf16_f32 %0, %1, %2" : "=v"(r.u[0]) : "v"(a[0]), "v"(a[1]));
    asm("v_cvt_pk_bf16_f32 %0, %1, %2" : "=v"(r.u[1]) : "v"(a[2]), "v"(a[3]));
    asm("v_cvt_pk_bf16_f32 %0, %1, %2" : "=v"(r.u[2]) : "v"(b[0]), "v"(b[1]));
    asm("v_cvt_pk_bf16_f32 %0, %1, %2" : "=v"(r.u[3]) : "v"(b[2]), "v"(b[3]));
    return r.s;
}

// async global->LDS DMA, 16B/lane.  LDS dest wave-uniform base + lane*16;
// global src per-lane (pre-swizzled).
__device__ __forceinline__ void dma16(const void* g, void* l) {
    __builtin_amdgcn_global_load_lds(
        (const __attribute__((address_space(1))) unsigned int*)g,
        (__attribute__((address_space(3))) unsigned int*)l,
        16, 0, 0);
}

// ---------------------------------------------------------------------------
// Kernel 0: convert inputs f32[240][4096] -> bf16 [256][4096], rows >=240 = 0
// ---------------------------------------------------------------------------
__global__ __launch_bounds__(256) void cvt_kernel(
    const float* __restrict__ in1, const float* __restrict__ in2,
    short* __restrict__ A1, short* __restrict__ A2)
{
    const int i = blockIdx.x * 256 + threadIdx.x;   // chunk of 8 elems
    const float* __restrict__ src = blockIdx.y ? in2 : in1;
    short* __restrict__ dst = blockIdx.y ? A2 : A1;
    const int r = i >> 9;
    const int c = (i & 511) * 8;
    s16x8 v = (s16x8){0,0,0,0,0,0,0,0};
    if (r < SEQ) {
        float4 a = *(const float4*)&src[(size_t)r * HID + c];
        float4 b = *(const float4*)&src[(size_t)r * HID + c + 4];
        v = cvt8(a, b);
    }
    *(s16x8*)&dst[(size_t)r * HID + c] = v;
}

// ---------------------------------------------------------------------------
// Kernel 1: QKV gemm partials — DMA staging + RAW-BARRIER COUNTED-VMCNT loop
// (T3-min + T4, m201 pattern).  vmcnt NEVER drains to 0 in the main loop.
// BM=256, BN=64, BK=32; LDS 48KB (As 2x16K bf16, Bs 2x8K f32) -> 3 blocks/CU.
// grid (64, 3, KS) = 768 @ KS=4 = exactly 3/CU.
// Per step/wave: 12 ds_read_b128 + 16 MFMA + 16 cvt_pk.
// Pipeline: DMA depth 2.  Step t: {reads+MFMA from buf b; lgkmcnt(0);
//   barrier; issue DMA(t+2)->buf b; vmcnt(6) [retires DMA(t+1)]; barrier}.
// v (g==2) partials stored TRANSPOSED: pvt[z][n][m].
// ---------------------------------------------------------------------------
__global__ __launch_bounds__(256, 3) void qkv_gemm(
    const short* __restrict__ A1, const short* __restrict__ A2,
    const float* __restrict__ Wq, const float* __restrict__ Wk,
    const float* __restrict__ Wv,
    float* __restrict__ pqk, float* __restrict__ pvt, int KC)
{
    const int g  = blockIdx.y;
    const int z  = blockIdx.z;
    const int nb = blockIdx.x * 64;
    const short* __restrict__ A = (g == 0) ? A1 : A2;
    const float* __restrict__ W = (g == 0) ? Wq : (g == 1) ? Wk : Wv;

    const int tid  = threadIdx.x;
    const int lane = tid & 63;
    const int w    = tid >> 6;      // wave owns A rows w*64 .. +63
    const int lr   = lane & 15;
    const int lg   = lane >> 4;

    __shared__ short As[2][256 * 32];   // 2 x 16 KB
    __shared__ float Bs[2][64 * 32];    // 2 x  8 KB

    f32x4 acc[4][4];
    #pragma unroll
    for (int m = 0; m < 4; ++m)
        #pragma unroll
        for (int n = 0; n < 4; ++n)
            acc[m][n] = (f32x4){0.f, 0.f, 0.f, 0.f};

    // --- per-lane DMA source pointers (pre-swizzled within each row) ---
    const short* gA[4];
    #pragma unroll
    for (int j = 0; j < 4; ++j) {
        const int row = (j * 4 + w) * 16 + (lane >> 2);
        const int c   = (lane & 3) ^ ((row >> 1) & 3);
        gA[j] = A + (size_t)row * HID + (size_t)z * KC + c * 8;
    }
    const float* gW[2];
    #pragma unroll
    for (int j = 0; j < 2; ++j) {
        const int row = (j * 4 + w) * 8 + (lane >> 3);
        const int c   = (lane & 7) ^ (row & 7);
        gW[j] = W + (size_t)(nb + row) * HID + (size_t)z * KC + c * 4;
    }

    // --- LDS fragment-read offsets (same XOR as source pre-swizzle) ---
    int aoff[4];
    #pragma unroll
    for (int m = 0; m < 4; ++m) {
        const int row = w * 64 + m * 16 + lr;
        aoff[m] = row * 32 + ((lg ^ ((row >> 1) & 3)) * 8);     // shorts
    }
    int boff0[4], boff1[4];
    #pragma unroll
    for (int n = 0; n < 4; ++n) {
        const int row = n * 16 + lr;
        boff0[n] = row * 32 + (((2 * lg)     ^ (row & 7)) * 4); // floats
        boff1[n] = row * 32 + (((2 * lg + 1) ^ (row & 7)) * 4);
    }

#define ISSUE(bb) {                                                          \
    _Pragma("unroll")                                                        \
    for (int j = 0; j < 4; ++j) {                                            \
        dma16(gA[j], &As[bb][(j * 4 + w) * 512]);  gA[j] += 32; }            \
    _Pragma("unroll")                                                        \
    for (int j = 0; j < 2; ++j) {                                            \
        dma16(gW[j], &Bs[bb][(j * 4 + w) * 256]);  gW[j] += 32; } }

    // prologue: 2 tiles in flight, wait only the first
    ISSUE(0)
    ISSUE(1)
    asm volatile("s_waitcnt vmcnt(6)" ::: "memory");
    __builtin_amdgcn_s_barrier();
    __builtin_amdgcn_sched_barrier(0);

    const int NIT = KC / 32;
    for (int t = 0; t < NIT; ++t) {
        const int b = t & 1;

        s16x8 af[4], bf[4];
        #pragma unroll
        for (int m = 0; m < 4; ++m)
            af[m] = *(const s16x8*)&As[b][aoff[m]];
        #pragma unroll
        for (int n = 0; n < 4; ++n) {
            f32x4 x0 = *(const f32x4*)&Bs[b][boff0[n]];
            f32x4 x1 = *(const f32x4*)&Bs[b][boff1[n]];
            bf[n] = cvtpk8(x0, x1);
        }
        #pragma unroll
        for (int m = 0; m < 4; ++m)
            #pragma unroll
            for (int n = 0; n < 4; ++n)
                acc[m][n] = __builtin_amdgcn_mfma_f32_16x16x32_bf16(af[m], bf[n], acc[m][n], 0, 0, 0);

        if (t + 1 < NIT) {
            // seal this wave's LDS reads of buf b, then block-wide seal
            asm volatile("s_waitcnt lgkmcnt(0)" ::: "memory");
            __builtin_amdgcn_s_barrier();           // all reads of buf b done
            __builtin_amdgcn_sched_barrier(0);
            if (t + 2 < NIT) {
                ISSUE(b)                            // DMA tile t+2 -> buf b
                asm volatile("s_waitcnt vmcnt(6)" ::: "memory");  // retire t+1
            } else {
                asm volatile("s_waitcnt vmcnt(0)" ::: "memory");  // last: drain
            }
            __builtin_amdgcn_s_barrier();           // publish buf b^1
            __builtin_amdgcn_sched_barrier(0);
        }
    }
#undef ISSUE

    if (g == 2) {
        // transposed partial store: pvt[z][n][m]
        float* pout = pvt + (size_t)z * HID * SEQ;
        #pragma unroll
        for (int m = 0; m < 4; ++m) {
            const int row0 = w * 64 + m * 16 + lg * 4;
            if (row0 >= SEQ) continue;
            #pragma unroll
            for (int n = 0; n < 4; ++n) {
                const int col = nb + n * 16 + lr;
                float4 o = make_float4(acc[m][n][0], acc[m][n][1], acc[m][n][2], acc[m][n][3]);
                *(float4*)&pout[(size_t)col * SEQ + row0] = o;
            }
        }
    } else {
        float* pout = pqk + (size_t)(z * 2 + g) * SEQ * HID;
        #pragma unroll
        for (int m = 0; m < 4; ++m) {
            const int row0 = w * 64 + m * 16 + lg * 4;
            if (row0 >= SEQ) continue;
            #pragma unroll
            for (int n = 0; n < 4; ++n) {
                const int col = nb + n * 16 + lr;
                #pragma unroll
                for (int r = 0; r < 4; ++r)
                    pout[(size_t)(row0 + r) * HID + col] = acc[m][n][r];
            }
        }
    }
}

// ---------------------------------------------------------------------------
// Kernel 2: reduce q/k partials + bias -> bf16 row-major
// ---------------------------------------------------------------------------
__global__ __launch_bounds__(256) void reduce_qk(
    const float* __restrict__ pqk,
    const float* __restrict__ bq, const float* __restrict__ bk,
    short* __restrict__ qb, short* __restrict__ kb, int KS)
{
    const int g   = blockIdx.y;
    const int idx = blockIdx.x * 256 + threadIdx.x;   // f32x4 index
    f32x4 s = (f32x4){0.f, 0.f, 0.f, 0.f};
    for (int z = 0; z < KS; ++z)
        s += *(const f32x4*)&pqk[(size_t)(z * 2 + g) * SEQ * HID + (size_t)idx * 4];
    const int n = (idx * 4) & (HID - 1);
    const float* bias = g ? bk : bq;
    s += *(const f32x4*)&bias[n];
    short* ob = g ? kb : qb;
    s16x4 o = (s16x4){f2bf(s[0]), f2bf(s[1]), f2bf(s[2]), f2bf(s[3])};
    *(s16x4*)&ob[(size_t)idx * 4] = o;
}

// ---------------------------------------------------------------------------
// Kernel 3: reduce transposed v partials + bias -> vtb bf16 [4096][240]
// ---------------------------------------------------------------------------
__global__ __launch_bounds__(256) void reduce_v(
    const float* __restrict__ pvt, const float* __restrict__ bv,
    short* __restrict__ vtb, int KS)
{
    const int idx = blockIdx.x * 256 + threadIdx.x;   // f32x4 index over [4096][240]
    f32x4 s = (f32x4){0.f, 0.f, 0.f, 0.f};
    for (int z = 0; z < KS; ++z)
        s += *(const f32x4*)&pvt[(size_t)z * HID * SEQ + (size_t)idx * 4];
    const int n = idx / 60;                           // 60 f32x4 per 240-row
    const float b = bv[n];
    s16x4 o = (s16x4){f2bf(s[0] + b), f2bf(s[1] + b), f2bf(s[2] + b), f2bf(s[3] + b)};
    *(s16x4*)&vtb[(size_t)idx * 4] = o;
}

// ---------------------------------------------------------------------------
// Kernel 4: scores + softmax.  4 waves/block, jt-split, LDS cross-wave
// softmax combine.  P^T stored bf16: ptb[h][j][i].
// ---------------------------------------------------------------------------
__global__ __launch_bounds__(256) void scores_kernel(
    const short* __restrict__ qb, const short* __restrict__ kb,
    short* __restrict__ ptb)
{
    const int it   = blockIdx.x;     // 0..14
    const int h    = blockIdx.y;     // 0..15
    const int tid  = threadIdx.x;
    const int lane = tid & 63;
    const int w    = tid >> 6;
    const int lr   = lane & 15;
    const int lg   = lane >> 4;
    const int jt0  = w * 4;
    const int NJT  = (w < 3) ? 4 : 3;

    __shared__ float redmax[4][16];
    __shared__ float redsum[4][16];

    f32x4 acc[4];
    #pragma unroll
    for (int j = 0; j < 4; ++j) acc[j] = (f32x4){0.f, 0.f, 0.f, 0.f};

    const int ib = it * 16;
    const short* qrow = &qb[(size_t)(ib + lr) * HID + h * HD + lg * 8];

    for (int d0 = 0; d0 < HD; d0 += 32) {
        s16x8 afr = *(const s16x8*)&qrow[d0];
        #pragma unroll
        for (int j = 0; j < 4; ++j) {
            if (j < NJT) {
                s16x8 bfr = *(const s16x8*)&kb[(size_t)((jt0 + j) * 16 + lr) * HID + h * HD + d0 + lg * 8];
                acc[j] = __builtin_amdgcn_mfma_f32_16x16x32_bf16(afr, bfr, acc[j], 0, 0, 0);
            }
        }
    }

    const float sc = 0.0625f;
    #pragma unroll
    for (int j = 0; j < 4; ++j) acc[j] *= sc;

    // phase 1: wave-local max per i, publish
    #pragma unroll
    for (int r = 0; r < 4; ++r) {
        float mx = -1e30f;
        #pragma unroll
        for (int j = 0; j < 4; ++j) if (j < NJT) mx = fmaxf(mx, acc[j][r]);
        #pragma unroll
        for (int s = 1; s < 16; s <<= 1) mx = fmaxf(mx, __shfl_xor(mx, s, 64));
        if (lr == 0) redmax[w][lg * 4 + r] = mx;
    }
    __syncthreads();
    // phase 2: global max, exp, wave-local sum, publish
    #pragma unroll
    for (int r = 0; r < 4; ++r) {
        const int i = lg * 4 + r;
        float mx = fmaxf(fmaxf(redmax[0][i], redmax[1][i]),
                         fmaxf(redmax[2][i], redmax[3][i]));
        float sum = 0.f;
        #pragma unroll
        for (int j = 0; j < 4; ++j) {
            if (j < NJT) {
                float e = expf(acc[j][r] - mx);
                acc[j][r] = e;
                sum += e;
            }
        }
        #pragma unroll
        for (int s = 1; s < 16; s <<= 1) sum += __shfl_xor(sum, s, 64);
        if (lr == 0) redsum[w][i] = sum;
    }
    __syncthreads();
    // phase 3: normalize + store bf16 (4 consecutive i per lane)
    #pragma unroll
    for (int r = 0; r < 4; ++r) {
        const int i = lg * 4 + r;
        const float inv = 1.f / (redsum[0][i] + redsum[1][i] + redsum[2][i] + redsum[3][i]);
        #pragma unroll
        for (int j = 0; j < 4; ++j) if (j < NJT) acc[j][r] *= inv;
    }
    #pragma unroll
    for (int j = 0; j < 4; ++j) {
        if (j < NJT) {
            const int jj = (jt0 + j) * 16 + lr;
            s16x4 o = (s16x4){f2bf(acc[j][0]), f2bf(acc[j][1]), f2bf(acc[j][2]), f2bf(acc[j][3])};
            *(s16x4*)&ptb[(size_t)(h * SEQ + jj) * SEQ + ib + lg * 4] = o;
        }
    }
}

// ---------------------------------------------------------------------------
// Kernel 5: O = P^T V per head, 4 waves/block jt-split, all-bf16 inputs.
// ---------------------------------------------------------------------------
__global__ __launch_bounds__(256) void pv_kernel(
    const short* __restrict__ ptb, const short* __restrict__ vtb,
    float* __restrict__ out)
{
    const int dt   = blockIdx.x;     // 0..15
    const int h    = blockIdx.y;
    const int tid  = threadIdx.x;
    const int lane = tid & 63;
    const int w    = tid >> 6;
    const int lr   = lane & 15;
    const int lg   = lane >> 4;
    const int NJT  = (w < 3) ? 4 : 3;

    f32x4 acc[4];
    #pragma unroll
    for (int j = 0; j < 4; ++j) acc[j] = (f32x4){0.f, 0.f, 0.f, 0.f};

    const short* vrow = &vtb[(size_t)(h * HD + dt * 16 + lr) * SEQ + lg * 8];

    for (int i0 = 0; i0 < 256; i0 += 32) {
        const bool ok = (i0 + lg * 8) < SEQ;
        s16x8 bfr = (s16x8){0,0,0,0,0,0,0,0};
        if (ok) bfr = *(const s16x8*)&vrow[i0];
        #pragma unroll
        for (int j = 0; j < 4; ++j) {
            if (j < NJT) {
                const int jt = w + j * 4;
                s16x8 afr = (s16x8){0,0,0,0,0,0,0,0};
                if (ok) afr = *(const s16x8*)&ptb[(size_t)(h * SEQ + jt * 16 + lr) * SEQ + i0 + lg * 8];
                acc[j] = __builtin_amdgcn_mfma_f32_16x16x32_bf16(afr, bfr, acc[j], 0, 0, 0);
            }
        }
    }

    #pragma unroll
    for (int j = 0; j < 4; ++j) {
        if (j < NJT) {
            const int jt = w + j * 4;
            #pragma unroll
            for (int r = 0; r < 4; ++r)
                out[(size_t)(jt * 16 + lg * 4 + r) * HID + h * HD + dt * 16 + lr] = acc[j][r];
        }
    }
}

extern "C" void kernel_launch(void* const* d_in, const int* in_sizes, int n_in,
                              void* d_out, int out_size, void* d_ws, size_t ws_size,
                              hipStream_t stream) {
    const float* in1 = (const float*)d_in[0];
    const float* in2 = (const float*)d_in[1];
    const float* Wq  = (const float*)d_in[2];
    const float* bq  = (const float*)d_in[3];
    const float* Wk  = (const float*)d_in[4];
    const float* bk  = (const float*)d_in[5];
    const float* Wv  = (const float*)d_in[6];
    const float* bv  = (const float*)d_in[7];
    float* out = (float*)d_out;

    char* w = (char*)d_ws;
    short* A1  = (short*)w;  w += (size_t)256 * HID * 2;        // 2 MB
    short* A2  = (short*)w;  w += (size_t)256 * HID * 2;        // 2 MB
    short* qb  = (short*)w;  w += (size_t)SEQ * HID * 2;        // 1.97 MB
    short* kb  = (short*)w;  w += (size_t)SEQ * HID * 2;
    short* vtb = (short*)w;  w += (size_t)HID * SEQ * 2;
    short* ptb = (short*)w;  w += (size_t)NH * SEQ * SEQ * 2;   // 1.84 MB
    float* pqk = (float*)w;
    const size_t fixed  = (size_t)(w - (char*)d_ws);
    const size_t perKS  = ((size_t)2 * SEQ * HID + (size_t)HID * SEQ) * sizeof(float); // 11.8 MB

    int KS = 1;
    if (fixed + 4 * perKS <= ws_size)      KS = 4;
    else if (fixed + 2 * perKS <= ws_size) KS = 2;
    const int KC = HID / KS;
    float* pvt = pqk + (size_t)KS * 2 * SEQ * HID;

    cvt_kernel<<<dim3(512, 2), 256, 0, stream>>>(in1, in2, A1, A2);
    qkv_gemm<<<dim3(64, 3, KS), 256, 0, stream>>>(A1, A2, Wq, Wk, Wv, pqk, pvt, KC);
    reduce_qk<<<dim3(960, 2), 256, 0, stream>>>(pqk, bq, bk, qb, kb, KS);
    reduce_v<<<960, 256, 0, stream>>>(pvt, bv, vtb, KS);
    scores_kernel<<<dim3(15, 16), 256, 0, stream>>>(qb, kb, ptb);
    pv_kernel<<<dim3(16, 16), 256, 0, stream>>>(ptb, vtb, out);
}